// Round 11
// baseline (71.702 us; speedup 1.0000x reference)
//
#include <hip/hip_runtime.h>
#include <hip/hip_bf16.h>

// Fused GAT layer, round 11: R10 + XCD-batch partitioning.
// ONLY change vs R10: block->work mapping. HW round-robins blockIdx%8 -> XCD,
// so b = bid & 7 gives each XCD exactly one batch: x reads stream x[b] (16MB)
// sequentially, out/att writes hit a private contiguous 33MB region per XCD.
// Per-block access patterns byte-identical to R10 (which passed at 68.4us).
// Wave = (b, n, g-half); barrier-free MFMA; out through 36KB padded LDS so
// write segments are 256B contiguous; att direct (256B runs); all NT stores.

#define NK 32768
#define NEG_SLOPE 0.2f
#define LSTR 36                     // LDS k-stride (floats); 16B-aligned, bank-optimal

using f32x4 = __attribute__((ext_vector_type(4))) float;
using s16x8 = __attribute__((ext_vector_type(8))) short;

__global__ __launch_bounds__(256, 4) void fused_gat_wave(
    const float* __restrict__ x,
    const int*   __restrict__ core_types,
    const int*   __restrict__ target_types,
    const float* __restrict__ W,
    const float* __restrict__ a_pair,
    float* __restrict__ out,
    float* __restrict__ att_out)
{
    __shared__ float lds[2 * 128 * LSTR];     // 36864 B: [nl][g][k(pad 36)]

    const int t    = threadIdx.x;
    const int lane = t & 63, l15 = lane & 15, l4 = lane >> 4;
    const int wv   = t >> 6;                  // 0..3
    const int nl   = wv >> 1, half = wv & 1;  // wave -> (n-local, g-half)
    const int b    = blockIdx.x & 7;          // XCD-partition: one batch per XCD
    const int n0   = (blockIdx.x >> 3) * 2;
    const int n    = n0 + nl;

    const float* xb = x + (size_t)b * 128 * NK + n * 32;   // + f*NK + k
    const int    g0 = half * 64 + 4 * l15;                 // lane's base g; g = g0 + gt
    const float* wb = W + g0;                              // + f*128

    // ---- MFMA fs-loop: acc[mt][gt], k = 16mt + l4*4 + r, g = g0 + gt
    f32x4 acc[2][4];
    #pragma unroll
    for (int mt = 0; mt < 2; ++mt)
        #pragma unroll
        for (int gt = 0; gt < 4; ++gt) acc[mt][gt] = (f32x4){0.f, 0.f, 0.f, 0.f};

    #pragma unroll
    for (int fs = 0; fs < 4; ++fs) {
        const int f0 = fs * 32 + l4 * 8;

        // W: one float4 per f-row (covers gt=0..3), repack to bf16 fragments
        s16x8 bfrag[4];
        #pragma unroll
        for (int fp = 0; fp < 4; ++fp) {                   // f = f0 + 2fp (+1)
            const f32x4 we = *(const f32x4*)&wb[(size_t)(f0 + 2 * fp)     * 128];
            const f32x4 wo = *(const f32x4*)&wb[(size_t)(f0 + 2 * fp + 1) * 128];
            #pragma unroll
            for (int gt = 0; gt < 4; ++gt) {
                __hip_bfloat162 h2 = __float22bfloat162_rn(make_float2(we[gt], wo[gt]));
                ((unsigned*)&bfrag[gt])[fp] = *(const unsigned*)&h2;
            }
        }

        s16x8 afrag[2];
        #pragma unroll
        for (int mt = 0; mt < 2; ++mt)
            #pragma unroll
            for (int i2 = 0; i2 < 4; ++i2) {
                const int f = f0 + 2 * i2;
                __hip_bfloat162 h2 = __float22bfloat162_rn(make_float2(
                    xb[(size_t)f * NK + 16 * mt + l15],
                    xb[(size_t)(f + 1) * NK + 16 * mt + l15]));
                ((unsigned*)&afrag[mt])[i2] = *(const unsigned*)&h2;
            }

        #pragma unroll
        for (int mt = 0; mt < 2; ++mt)
            #pragma unroll
            for (int gt = 0; gt < 4; ++gt)
                acc[mt][gt] = __builtin_amdgcn_mfma_f32_16x16x32_bf16(
                    afrag[mt], bfrag[gt], acc[mt][gt], 0, 0, 0);
    }

    // ---- e = leaky_relu(Wh * a)   (a_pair: one float4 per (mt,r))
    const int cc = core_types[b * 1024 + n];
    float ev[2][4][4];
    #pragma unroll
    for (int mt = 0; mt < 2; ++mt) {
        const int kb = 16 * mt + l4 * 4;
        const int4 tt4 = *(const int4*)&target_types[((size_t)(b * 1024 + n)) * 32 + kb];
        const int ttv[4] = {tt4.x, tt4.y, tt4.z, tt4.w};
        #pragma unroll
        for (int r = 0; r < 4; ++r) {
            const int tv = ttv[r];
            const int lo = min(cc, tv), hi = max(cc, tv);
            const int idx = lo * (17 - lo) / 2 + (hi - lo);
            const f32x4 a4 = *(const f32x4*)&a_pair[idx * 128 + g0];
            #pragma unroll
            for (int gt = 0; gt < 4; ++gt) {
                const float e = acc[mt][gt][r] * a4[gt];
                ev[mt][gt][r] = e > 0.f ? e : NEG_SLOPE * e;
            }
        }
    }

    // ---- softmax over k (8 regs x 4-lane group: xor 16, 32), per gt
    #pragma unroll
    for (int gt = 0; gt < 4; ++gt) {
        float mx = -1e30f;
        #pragma unroll
        for (int mt = 0; mt < 2; ++mt)
            #pragma unroll
            for (int r = 0; r < 4; ++r) mx = fmaxf(mx, ev[mt][gt][r]);
        mx = fmaxf(mx, __shfl_xor(mx, 16));
        mx = fmaxf(mx, __shfl_xor(mx, 32));
        float sm = 0.f;
        #pragma unroll
        for (int mt = 0; mt < 2; ++mt)
            #pragma unroll
            for (int r = 0; r < 4; ++r) {
                const float p = __expf(ev[mt][gt][r] - mx);
                ev[mt][gt][r] = p;
                sm += p;
            }
        sm += __shfl_xor(sm, 16);
        sm += __shfl_xor(sm, 32);
        const float inv = __fdividef(1.f, sm);
        #pragma unroll
        for (int mt = 0; mt < 2; ++mt)
            #pragma unroll
            for (int r = 0; r < 4; ++r) ev[mt][gt][r] *= inv;
    }

    // ---- att stores direct (256B runs, non-temporal)
    #pragma unroll
    for (int mt = 0; mt < 2; ++mt) {
        const int kb = 16 * mt + l4 * 4;
        #pragma unroll
        for (int r = 0; r < 4; ++r) {
            f32x4 av = {ev[mt][0][r], ev[mt][1][r], ev[mt][2][r], ev[mt][3][r]};
            __builtin_nontemporal_store(
                av, (f32x4*)&att_out[(((size_t)(b * 1024 + n)) * 32 + kb + r) * 128 + g0]);
        }
    }

    // ---- out values -> LDS [nl][g][k] (pad 36: all phases bank-throughput-optimal)
    #pragma unroll
    for (int mt = 0; mt < 2; ++mt) {
        const int kb = 16 * mt + l4 * 4;
        #pragma unroll
        for (int gt = 0; gt < 4; ++gt) {
            f32x4 ov;
            #pragma unroll
            for (int r = 0; r < 4; ++r) {
                const float hh = ev[mt][gt][r] * acc[mt][gt][r];
                ov[r] = hh > 0.f ? hh : __expf(hh) - 1.f;
            }
            *(f32x4*)&lds[(nl * 128 + g0 + gt) * LSTR + kb] = ov;
        }
    }

    __syncthreads();

    // ---- cooperative g-major out stores: per instr 4 x 256B contiguous segments
    {
        const int hi  = t >> 4;          // 0..15 : g sub-index
        const int nl2 = (t >> 3) & 1;    // n-local
        const int kq  = (t & 7) * 4;     // k quad
        float* ob = out + (size_t)b * 128 * NK + (size_t)(n0 + nl2) * 32 + kq;
        #pragma unroll
        for (int i = 0; i < 8; ++i) {
            const int g = i * 16 + hi;
            const f32x4 v = *(const f32x4*)&lds[(nl2 * 128 + g) * LSTR + kq];
            __builtin_nontemporal_store(v, (f32x4*)&ob[(size_t)g * NK]);
        }
    }
}

extern "C" void kernel_launch(void* const* d_in, const int* in_sizes, int n_in,
                              void* d_out, int out_size, void* d_ws, size_t ws_size,
                              hipStream_t stream) {
    const float* x    = (const float*)d_in[0];
    const int*   core = (const int*)  d_in[1];
    const int*   tgt  = (const int*)  d_in[2];
    const float* W    = (const float*)d_in[3];
    const float* ap   = (const float*)d_in[4];
    // d_in[5]/d_in[6] (lin_w, lin_b) only feed attention_viz, which is not returned.

    float* out_p = (float*)d_out;                       // (8,128,1024,32)
    float* att_p = out_p + (size_t)8 * 128 * 1024 * 32; // (8,1024,32,128)

    fused_gat_wave<<<dim3(4096), dim3(256), 0, stream>>>(x, core, tgt, W, ap, out_p, att_p);
}

// Round 12
// 67.780 us; speedup vs baseline: 1.0579x; 1.0579x over previous
//
#include <hip/hip_runtime.h>
#include <hip/hip_bf16.h>

// Fused GAT layer, round 12: R10 + 4n-per-block (512 thr, 8 waves) to widen out
// write segments 256B -> 512B. Per-wave compute identical to R10 (wave = (nl,half),
// nl in 0..3). LDS out-bounce [4n][128g][36pad] fp32 = 73.7KB (gfx950 allows >64KB
// static LDS; 2 blocks/CU = 16 waves/CU, R5-neutral). Default block mapping
// (R11's XCD remap regressed; R10 mapping restored). att direct NT (256B runs,
// region now 64KB contiguous/block). Coop out stores: 512B contiguous per g-plane.

#define NK 32768
#define NEG_SLOPE 0.2f
#define LSTR 36                     // LDS k-stride (floats); 16B-aligned, bank-proven (R10)

using f32x4 = __attribute__((ext_vector_type(4))) float;
using s16x8 = __attribute__((ext_vector_type(8))) short;

__global__ __launch_bounds__(512, 4) void fused_gat_wave(
    const float* __restrict__ x,
    const int*   __restrict__ core_types,
    const int*   __restrict__ target_types,
    const float* __restrict__ W,
    const float* __restrict__ a_pair,
    float* __restrict__ out,
    float* __restrict__ att_out)
{
    __shared__ float lds[4 * 128 * LSTR];     // 73728 B: [nl][g][k(pad 36)]

    const int t    = threadIdx.x;
    const int lane = t & 63, l15 = lane & 15, l4 = lane >> 4;
    const int wv   = t >> 6;                  // 0..7
    const int nl   = wv >> 1, half = wv & 1;  // wave -> (n-local 0..3, g-half)
    const int b    = blockIdx.x >> 8;
    const int n0   = (blockIdx.x & 255) * 4;
    const int n    = n0 + nl;

    const float* xb = x + (size_t)b * 128 * NK + n * 32;   // + f*NK + k
    const int    g0 = half * 64 + 4 * l15;                 // lane's base g; g = g0 + gt
    const float* wb = W + g0;                              // + f*128

    // ---- MFMA fs-loop: acc[mt][gt], k = 16mt + l4*4 + r, g = g0 + gt
    f32x4 acc[2][4];
    #pragma unroll
    for (int mt = 0; mt < 2; ++mt)
        #pragma unroll
        for (int gt = 0; gt < 4; ++gt) acc[mt][gt] = (f32x4){0.f, 0.f, 0.f, 0.f};

    #pragma unroll
    for (int fs = 0; fs < 4; ++fs) {
        const int f0 = fs * 32 + l4 * 8;

        // W: one float4 per f-row (covers gt=0..3), repack to bf16 fragments
        s16x8 bfrag[4];
        #pragma unroll
        for (int fp = 0; fp < 4; ++fp) {                   // f = f0 + 2fp (+1)
            const f32x4 we = *(const f32x4*)&wb[(size_t)(f0 + 2 * fp)     * 128];
            const f32x4 wo = *(const f32x4*)&wb[(size_t)(f0 + 2 * fp + 1) * 128];
            #pragma unroll
            for (int gt = 0; gt < 4; ++gt) {
                __hip_bfloat162 h2 = __float22bfloat162_rn(make_float2(we[gt], wo[gt]));
                ((unsigned*)&bfrag[gt])[fp] = *(const unsigned*)&h2;
            }
        }

        s16x8 afrag[2];
        #pragma unroll
        for (int mt = 0; mt < 2; ++mt)
            #pragma unroll
            for (int i2 = 0; i2 < 4; ++i2) {
                const int f = f0 + 2 * i2;
                __hip_bfloat162 h2 = __float22bfloat162_rn(make_float2(
                    xb[(size_t)f * NK + 16 * mt + l15],
                    xb[(size_t)(f + 1) * NK + 16 * mt + l15]));
                ((unsigned*)&afrag[mt])[i2] = *(const unsigned*)&h2;
            }

        #pragma unroll
        for (int mt = 0; mt < 2; ++mt)
            #pragma unroll
            for (int gt = 0; gt < 4; ++gt)
                acc[mt][gt] = __builtin_amdgcn_mfma_f32_16x16x32_bf16(
                    afrag[mt], bfrag[gt], acc[mt][gt], 0, 0, 0);
    }

    // ---- e = leaky_relu(Wh * a)   (a_pair: one float4 per (mt,r))
    const int cc = core_types[b * 1024 + n];
    float ev[2][4][4];
    #pragma unroll
    for (int mt = 0; mt < 2; ++mt) {
        const int kb = 16 * mt + l4 * 4;
        const int4 tt4 = *(const int4*)&target_types[((size_t)(b * 1024 + n)) * 32 + kb];
        const int ttv[4] = {tt4.x, tt4.y, tt4.z, tt4.w};
        #pragma unroll
        for (int r = 0; r < 4; ++r) {
            const int tv = ttv[r];
            const int lo = min(cc, tv), hi = max(cc, tv);
            const int idx = lo * (17 - lo) / 2 + (hi - lo);
            const f32x4 a4 = *(const f32x4*)&a_pair[idx * 128 + g0];
            #pragma unroll
            for (int gt = 0; gt < 4; ++gt) {
                const float e = acc[mt][gt][r] * a4[gt];
                ev[mt][gt][r] = e > 0.f ? e : NEG_SLOPE * e;
            }
        }
    }

    // ---- softmax over k (8 regs x 4-lane group: xor 16, 32), per gt
    #pragma unroll
    for (int gt = 0; gt < 4; ++gt) {
        float mx = -1e30f;
        #pragma unroll
        for (int mt = 0; mt < 2; ++mt)
            #pragma unroll
            for (int r = 0; r < 4; ++r) mx = fmaxf(mx, ev[mt][gt][r]);
        mx = fmaxf(mx, __shfl_xor(mx, 16));
        mx = fmaxf(mx, __shfl_xor(mx, 32));
        float sm = 0.f;
        #pragma unroll
        for (int mt = 0; mt < 2; ++mt)
            #pragma unroll
            for (int r = 0; r < 4; ++r) {
                const float p = __expf(ev[mt][gt][r] - mx);
                ev[mt][gt][r] = p;
                sm += p;
            }
        sm += __shfl_xor(sm, 16);
        sm += __shfl_xor(sm, 32);
        const float inv = __fdividef(1.f, sm);
        #pragma unroll
        for (int mt = 0; mt < 2; ++mt)
            #pragma unroll
            for (int r = 0; r < 4; ++r) ev[mt][gt][r] *= inv;
    }

    // ---- att stores direct (256B runs, non-temporal; block region 64KB contiguous)
    #pragma unroll
    for (int mt = 0; mt < 2; ++mt) {
        const int kb = 16 * mt + l4 * 4;
        #pragma unroll
        for (int r = 0; r < 4; ++r) {
            f32x4 av = {ev[mt][0][r], ev[mt][1][r], ev[mt][2][r], ev[mt][3][r]};
            __builtin_nontemporal_store(
                av, (f32x4*)&att_out[(((size_t)(b * 1024 + n)) * 32 + kb + r) * 128 + g0]);
        }
    }

    // ---- out values -> LDS [nl][g][k] (pad 36: bank pattern proven in R10)
    #pragma unroll
    for (int mt = 0; mt < 2; ++mt) {
        const int kb = 16 * mt + l4 * 4;
        #pragma unroll
        for (int gt = 0; gt < 4; ++gt) {
            f32x4 ov;
            #pragma unroll
            for (int r = 0; r < 4; ++r) {
                const float hh = ev[mt][gt][r] * acc[mt][gt][r];
                ov[r] = hh > 0.f ? hh : __expf(hh) - 1.f;
            }
            *(f32x4*)&lds[(nl * 128 + g0 + gt) * LSTR + kb] = ov;
        }
    }

    __syncthreads();

    // ---- cooperative g-major out stores: 512B contiguous per g-plane per block
    {
        const int kq  = (t & 7) * 4;     // k quad 0..28
        const int nl2 = (t >> 3) & 3;    // n-local 0..3
        const int gs  = t >> 5;          // g sub-index 0..15
        float* ob = out + (size_t)b * 128 * NK + (size_t)(n0 + nl2) * 32 + kq;
        #pragma unroll
        for (int i = 0; i < 8; ++i) {
            const int g = i * 16 + gs;
            const f32x4 v = *(const f32x4*)&lds[(nl2 * 128 + g) * LSTR + kq];
            __builtin_nontemporal_store(v, (f32x4*)&ob[(size_t)g * NK]);
        }
    }
}

extern "C" void kernel_launch(void* const* d_in, const int* in_sizes, int n_in,
                              void* d_out, int out_size, void* d_ws, size_t ws_size,
                              hipStream_t stream) {
    const float* x    = (const float*)d_in[0];
    const int*   core = (const int*)  d_in[1];
    const int*   tgt  = (const int*)  d_in[2];
    const float* W    = (const float*)d_in[3];
    const float* ap   = (const float*)d_in[4];
    // d_in[5]/d_in[6] (lin_w, lin_b) only feed attention_viz, which is not returned.

    float* out_p = (float*)d_out;                       // (8,128,1024,32)
    float* att_p = out_p + (size_t)8 * 128 * 1024 * 32; // (8,1024,32,128)

    fused_gat_wave<<<dim3(2048), dim3(512), 0, stream>>>(x, core, tgt, W, ap, out_p, att_p);
}